// Round 2
// baseline (918.366 us; speedup 1.0000x reference)
//
#include <hip/hip_runtime.h>

// Scattering_v3_tau: B=500000, C=30, NCON=8, NCC=3, NH=7
// Round 2: dtype-adaptive (bf16 vs f32) — round-1 NaN on output 0 (no-weight path)
// implies tau/mu decoded to NaN, i.e. buffers are f32 being misread as bf16.
// A 1-thread detector kernel sniffs the dtype (bit15 of raw words: always 0 for
// non-negative bf16 pairs, random for f32 mantissas) and all kernels branch
// wave-uniformly on the flag. Output dtype follows input dtype.

#define B_SZ 500000
#define C_SZ 30
#define BC   (B_SZ * C_SZ)
#define EPSF 1e-7f

__device__ __forceinline__ float bf2f(unsigned short u) {
    union { unsigned int i; float f; } v;
    v.i = ((unsigned int)u) << 16;
    return v.f;
}

__device__ __forceinline__ unsigned short f2bf(float f) {
    union { float f; unsigned int i; } v;
    v.f = f;
    unsigned int u = v.i;
    unsigned int r = u + 0x7fffu + ((u >> 16) & 1u);  // RNE
    return (unsigned short)(r >> 16);
}

// ---- dtype detector: flag=1 -> float32, flag=0 -> bf16 ----
__global__ void detect_dtype(const unsigned int* __restrict__ tau_raw,
                             int* __restrict__ flag) {
    if (threadIdx.x == 0 && blockIdx.x == 0) {
        unsigned int acc = 0;
        for (int i = 0; i < 256; ++i) acc |= tau_raw[i];
        *flag = (acc & 0x8000u) ? 1 : 0;
    }
}

// ---- weight conversion: 12 arrays -> 741 fp32 in ws ----
// layout: Wd1[63] bd1[7] Wdh[245] bdh[35] Wdo[21] bdo[3]
//         Wf1[56] bf1[7] Wfh[245] bfh[35] Wfo[21] bfo[3]
struct P12 { const void* p[12]; };

__global__ void cvt_weights(P12 ptrs, float* __restrict__ ws,
                            const int* __restrict__ flag) {
    int i = blockIdx.x * blockDim.x + threadIdx.x;
    if (i >= 741) return;
    const int sizes[12] = {63, 7, 245, 35, 21, 3, 56, 7, 245, 35, 21, 3};
    int off = i, seg = 0;
    while (seg < 11 && off >= sizes[seg]) { off -= sizes[seg]; ++seg; }
    if (*flag) {
        ws[i] = ((const float*)ptrs.p[seg])[off];
    } else {
        ws[i] = bf2f(((const unsigned short*)ptrs.p[seg])[off]);
    }
}

// ---- tiny MLP, fully unrolled ----
template <int IN>
__device__ __forceinline__ void mlp(const float* __restrict__ x,
                                    const float* __restrict__ W1,
                                    const float* __restrict__ b1,
                                    const float* __restrict__ Wh,
                                    const float* __restrict__ bh,
                                    const float* __restrict__ Wo,
                                    const float* __restrict__ bo,
                                    float* __restrict__ o) {
    float h[7];
#pragma unroll
    for (int j = 0; j < 7; ++j) {
        float a = b1[j];
#pragma unroll
        for (int i = 0; i < IN; ++i) a = fmaf(x[i], W1[j * IN + i], a);
        h[j] = fmaxf(a, 0.0f);
    }
#pragma unroll
    for (int l = 0; l < 5; ++l) {
        float h2[7];
#pragma unroll
        for (int j = 0; j < 7; ++j) {
            float a = bh[l * 7 + j];
#pragma unroll
            for (int i = 0; i < 7; ++i) a = fmaf(h[i], Wh[l * 49 + j * 7 + i], a);
            h2[j] = fmaxf(a, 0.0f);
        }
#pragma unroll
        for (int j = 0; j < 7; ++j) h[j] = h2[j];
    }
#pragma unroll
    for (int k = 0; k < 3; ++k) {
        float a = bo[k];
#pragma unroll
        for (int i = 0; i < 7; ++i) a = fmaf(h[i], Wo[k * 7 + i], a);
        o[k] = a;
    }
}

__global__ __launch_bounds__(256) void scatter_main(
    const void* __restrict__ tau_p,    // (B,C,8) bf16 or f32
    const void* __restrict__ mu_dir_p, // (B,1)
    const void* __restrict__ mu_dif_p, // (B,1)
    const float* __restrict__ ws,      // 741 fp32 weights
    const int* __restrict__ flag,      // 1 = f32, 0 = bf16
    void* __restrict__ out_p)          // out: [BC | BC | 3BC | 3BC]
{
    // coarse code (depends only on c) -> LDS, once per block
    __shared__ float cc_s[C_SZ * 3];
    int tid = threadIdx.x;
    if (tid < C_SZ * 3) {
        int c = tid / 3, j = tid - c * 3;
        const float sigma = 0.25f;
        const float c1 = 1.0f / (sigma * sqrtf(6.28f));
        float ii = (float)c * (1.0f / (float)(C_SZ - 1));
        float jj = (float)j * 0.5f;  // j/(NCC-1)
        float d = (ii - jj) * (1.0f / sigma);
        cc_s[tid] = c1 * __expf(-0.5f * d * d);
    }
    __syncthreads();

    int e = blockIdx.x * 256 + tid;
    if (e >= BC) return;
    int b = e / C_SZ;
    int c = e - b * C_SZ;

    int is_f32 = *flag;  // uniform load -> scalar branch

    float t0, t1, t2, t3, t4, t5, t6, t7, mu_d, mu_f;
    if (is_f32) {
        const float4* tf = (const float4*)tau_p;
        float4 a = tf[2 * e];
        float4 bq = tf[2 * e + 1];
        t0 = a.x; t1 = a.y; t2 = a.z; t3 = a.w;
        t4 = bq.x; t5 = bq.y; t6 = bq.z; t7 = bq.w;
        mu_d = ((const float*)mu_dir_p)[b];
        mu_f = ((const float*)mu_dif_p)[b];
    } else {
        uint4 t = ((const uint4*)tau_p)[e];
        t0 = bf2f((unsigned short)(t.x & 0xffffu));
        t1 = bf2f((unsigned short)(t.x >> 16));
        t2 = bf2f((unsigned short)(t.y & 0xffffu));
        t3 = bf2f((unsigned short)(t.y >> 16));
        t4 = bf2f((unsigned short)(t.z & 0xffffu));
        t5 = bf2f((unsigned short)(t.z >> 16));
        t6 = bf2f((unsigned short)(t.w & 0xffffu));
        t7 = bf2f((unsigned short)(t.w >> 16));
        mu_d = bf2f(((const unsigned short*)mu_dir_p)[b]);
        mu_f = bf2f(((const unsigned short*)mu_dif_p)[b]);
    }

    float rcp_d = __builtin_amdgcn_rcpf(mu_d + EPSF);
    float rcp_f = __builtin_amdgcn_rcpf(mu_f + EPSF);

    float tau_total = ((t0 + t1) + (t2 + t3)) + ((t4 + t5) + (t6 + t7));
    float t_direct = __expf(-tau_total * rcp_d);
    float t_diffuse = __expf(-tau_total * rcp_f);

    float cc0 = cc_s[c * 3 + 0], cc1 = cc_s[c * 3 + 1], cc2 = cc_s[c * 3 + 2];
    float s1 = (t3 + t4) + (t6 + t7);

    float xd[9] = {t0 * rcp_d, t1 * rcp_d, t5 * rcp_d, t2 * rcp_d,
                   s1 * rcp_d, mu_d, cc0, cc1, cc2};
    float xf[8] = {t0, t1, t5, t2, s1, cc0, cc1, cc2};

    float od[3], of_[3];
    mlp<9>(xd, ws + 0, ws + 63, ws + 70, ws + 315, ws + 350, ws + 371, od);
    mlp<8>(xf, ws + 374, ws + 430, ws + 437, ws + 682, ws + 717, ws + 738, of_);

    float md = fmaxf(fmaxf(od[0], od[1]), od[2]);
    float d0 = __expf(od[0] - md), d1 = __expf(od[1] - md), d2 = __expf(od[2] - md);
    float rd = __builtin_amdgcn_rcpf(d0 + d1 + d2);
    float mf = fmaxf(fmaxf(of_[0], of_[1]), of_[2]);
    float f0 = __expf(of_[0] - mf), f1 = __expf(of_[1] - mf), f2 = __expf(of_[2] - mf);
    float rf = __builtin_amdgcn_rcpf(f0 + f1 + f2);

    int od_base = 2 * BC + 3 * e;
    int of_base = 5 * BC + 3 * e;
    if (is_f32) {
        float* out = (float*)out_p;
        out[e] = t_direct;
        out[BC + e] = t_diffuse;
        out[od_base + 0] = d0 * rd;
        out[od_base + 1] = d1 * rd;
        out[od_base + 2] = d2 * rd;
        out[of_base + 0] = f0 * rf;
        out[of_base + 1] = f1 * rf;
        out[of_base + 2] = f2 * rf;
    } else {
        unsigned short* out = (unsigned short*)out_p;
        out[e] = f2bf(t_direct);
        out[BC + e] = f2bf(t_diffuse);
        out[od_base + 0] = f2bf(d0 * rd);
        out[od_base + 1] = f2bf(d1 * rd);
        out[od_base + 2] = f2bf(d2 * rd);
        out[of_base + 0] = f2bf(f0 * rf);
        out[of_base + 1] = f2bf(f1 * rf);
        out[of_base + 2] = f2bf(f2 * rf);
    }
}

extern "C" void kernel_launch(void* const* d_in, const int* in_sizes, int n_in,
                              void* d_out, int out_size, void* d_ws, size_t ws_size,
                              hipStream_t stream) {
    float* ws = (float*)d_ws;
    int* flag = (int*)((char*)d_ws + 4096);

    detect_dtype<<<1, 64, 0, stream>>>((const unsigned int*)d_in[0], flag);

    P12 p;
    for (int i = 0; i < 12; ++i) p.p[i] = d_in[3 + i];
    cvt_weights<<<1, 768, 0, stream>>>(p, ws, flag);

    int nblk = (BC + 255) / 256;
    scatter_main<<<nblk, 256, 0, stream>>>(
        d_in[0], d_in[1], d_in[2], ws, flag, d_out);
}